// Round 9
// baseline (393.827 us; speedup 1.0000x reference)
//
#include <hip/hip_runtime.h>
#include <hip/hip_bf16.h>

typedef unsigned short u16;
typedef unsigned int   u32;
typedef unsigned long long u64;
typedef long long      i64;
typedef __attribute__((ext_vector_type(8))) short short8;  // 8 bf16 raw
typedef __attribute__((ext_vector_type(4))) float f32x4;

#define HD 128   // hidden / input feature dim
#define OUTD 64  // final output dim
#define BSH 8            // bucket shift: 256 nodes per bucket (power of 2, <=8 for u32 pack!)
#define NBKT_MAX 512     // max buckets (N <= 128K; also keeps src in 24 bits)
#define PCHUNK 2048      // edges per block in partition phase 1
#define EPB 4096         // edges per block in bucket histogram
#define GCUR_STRIDE 16   // ints; 64 B padding to avoid atomic line contention

__device__ __forceinline__ float bf2f(u16 u){ union{u32 i; float f;} x; x.i=((u32)u)<<16; return x.f; }
__device__ __forceinline__ u16 f2bf(float f){ __hip_bfloat16 h=__float2bfloat16(f); return *reinterpret_cast<u16*>(&h); }
__device__ __forceinline__ float blo(u32 v){ union{u32 i; float f;} x; x.i=v<<16; return x.f; }
__device__ __forceinline__ float bhi(u32 v){ union{u32 i; float f;} x; x.i=v&0xffff0000u; return x.f; }

__device__ __forceinline__ short8 load8(const float* p){
  f32x4 lo = *reinterpret_cast<const f32x4*>(p);
  f32x4 hi = *reinterpret_cast<const f32x4*>(p + 4);
  short8 r;
  #pragma unroll
  for (int j=0;j<4;j++){ r[j]=(short)f2bf(lo[j]); r[4+j]=(short)f2bf(hi[j]); }
  return r;
}
__device__ __forceinline__ short8 load8(const u16* p){
  return *reinterpret_cast<const short8*>(p);
}

// index fetch that handles int32-vs-int64 delivery (flag: 1 = int32, 0 = int64)
__device__ __forceinline__ int idx_at(const void* p, int i, int is32){
  return is32 ? ((const int*)p)[i] : (int)((const i64*)p)[i];
}

// ---- zero-fill output (ws-too-small fallback signal) ----------------------
__global__ void k_zero_out(float* __restrict__ out, int n){
  int i = blockIdx.x*256 + threadIdx.x;
  if (i < n) out[i] = 0.f;
}

// ---- init (fused): blocks 0-1 pack W1/W2 -> bf16 fragment-major; block 2 =
// zero+detect dtype flags; blocks >=3 zero bcntp/pooled. -------------------
// flags[0]=edge int32?, flags[1]=batch int32?, flags[2]=batch unsorted?
__global__ __launch_bounds__(256) void k_init(
    const float* __restrict__ W1, u16* __restrict__ Wp1,
    const float* __restrict__ W2, u16* __restrict__ Wp2,
    const u32* __restrict__ ei, const u32* __restrict__ bw,
    int* __restrict__ flags, int* __restrict__ bcntp, float* __restrict__ pooled,
    int npairs_e, int npairs_b, int nbc, int npool)
{
  int t = threadIdx.x;
  if (blockIdx.x < 2){
    const float* W  = blockIdx.x ? W2 : W1;
    u16*         Wp = blockIdx.x ? Wp2 : Wp1;
    for (int u = t; u < 2048; u += 256){
      int lane = u & 63, tc = u >> 6;
      int tt = tc >> 2, c = tc & 3;
      int n = lane & 15, quad = lane >> 4;
      #pragma unroll
      for (int j=0;j<8;j++)
        Wp[(size_t)u*8 + j] = f2bf(W[(c*32 + quad*8 + j)*HD + tt*16 + n]);
    }
  } else if (blockIdx.x == 2){
    if (t < 16) flags[t] = 0;
    __syncthreads();
    for (int i=t; i<npairs_e; i+=256) if (ei[2*i+1] != 0) atomicOr(&flags[0], 1);
    for (int i=t; i<npairs_b; i+=256) if (bw[2*i+1] != 0) atomicOr(&flags[1], 1);
  } else {
    int i = (blockIdx.x-3)*256 + t;
    if (i < nbc)   bcntp[i] = 0;
    if (i < npool) pooled[i] = 0.f;
  }
}

// ---- bucket histogram + sortedness check ----------------------------------
// LDS 512-bin histogram/block, then 2 padded-line global atomics per thread.
// Per-NODE degrees are derived later, bucket-locally, in k_part2ex.
__global__ __launch_bounds__(256) void k_bucket_sorted(
    const void* __restrict__ batch, const void* __restrict__ ei,
    int* __restrict__ flags, int* __restrict__ bcntp, int n, int E, int NBc)
{
  __shared__ int hist[NBKT_MAX];
  int tid = threadIdx.x;
  if (blockIdx.x < NBc){
    int i = blockIdx.x*256 + tid;
    if (i < n-1){
      int is32 = flags[1];
      if (idx_at(batch, i, is32) > idx_at(batch, i+1, is32)) atomicOr(&flags[2], 1);
    }
    return;
  }
  hist[tid]=0; hist[tid+256]=0;
  __syncthreads();
  int base = (blockIdx.x - NBc)*EPB;
  int is32 = flags[0];
  #pragma unroll
  for (int k=0;k<EPB/256;k++){
    int e = base + k*256 + tid;
    if (e < E){
      int d = idx_at(ei, E + e, is32);   // dst = row 1
      atomicAdd(&hist[d>>BSH], 1);
    }
  }
  __syncthreads();
  int a0=hist[2*tid], a1=hist[2*tid+1];
  if (a0) atomicAdd(&bcntp[(2*tid)*GCUR_STRIDE],   a0);
  if (a1) atomicAdd(&bcntp[(2*tid+1)*GCUR_STRIDE], a1);
}

// ---- 512-bucket exclusive scan -> bucket bases (gcur for part1, bbase) ----
__global__ __launch_bounds__(256) void k_bucket_scan(
    const int* __restrict__ bcntp, int* __restrict__ gcur, int* __restrict__ bbase,
    int* __restrict__ row_ptr, int N, int E)
{
  __shared__ int scant[256];
  int t = threadIdx.x;
  int a0 = bcntp[(2*t)*GCUR_STRIDE], a1 = bcntp[(2*t+1)*GCUR_STRIDE];
  scant[t] = a0 + a1; __syncthreads();
  for (int o=1;o<256;o<<=1){ int x=(t>=o)?scant[t-o]:0; __syncthreads(); scant[t]+=x; __syncthreads(); }
  int pre = (t>0)?scant[t-1]:0;
  gcur[(2*t)*GCUR_STRIDE]   = pre;      bbase[2*t]   = pre;
  gcur[(2*t+1)*GCUR_STRIDE] = pre + a0; bbase[2*t+1] = pre + a0;
  if (t == 255){ bbase[512] = pre + a0 + a1; row_ptr[N] = E; }
}

// ---- phase 1: LDS-staged partition of edges into dst-buckets --------------
// STANDALONE kernel (low VGPR): r3's fat-fuse with the GEMM forced 144 VGPRs
// on these blocks and cut occupancy 8->3 blocks/CU (91 us, all pipes idle).
// pairs entry: src in bits [0,24), dst_local (d & 255) in bits [24,32).
__global__ __launch_bounds__(256) void k_part1(
    const void* __restrict__ ei, const int* __restrict__ flags,
    int* __restrict__ gcur, u32* __restrict__ pairs, int E)
{
  __shared__ int hist[NBKT_MAX];
  __shared__ int soff[NBKT_MAX];
  __shared__ int gb[NBKT_MAX];
  __shared__ int scant[256];
  __shared__ u32 stage[PCHUNK];
  __shared__ u16 sbkt[PCHUNK];

  int tid = threadIdx.x;
  hist[tid]=0; hist[tid+256]=0;
  __syncthreads();

  int base = blockIdx.x*PCHUNK;
  int is32 = flags[0];
  int d[PCHUNK/256], s[PCHUNK/256];
  #pragma unroll
  for (int k=0;k<PCHUNK/256;k++){
    int e = base + k*256 + tid;
    if (e < E){
      d[k]=idx_at(ei,E+e,is32); s[k]=idx_at(ei,e,is32);
      atomicAdd(&hist[d[k]>>BSH],1);
    } else d[k]=-1;
  }
  __syncthreads();

  // scan 512 buckets with 256 threads (2 each)
  int a0=hist[2*tid], a1=hist[2*tid+1];
  scant[tid]=a0+a1; __syncthreads();
  for (int o=1;o<256;o<<=1){ int x2=(tid>=o)?scant[tid-o]:0; __syncthreads(); scant[tid]+=x2; __syncthreads(); }
  int pre = (tid>0)?scant[tid-1]:0;
  soff[2*tid]=pre; soff[2*tid+1]=pre+a0;
  if (a0) gb[2*tid]   = atomicAdd(&gcur[(2*tid)*GCUR_STRIDE],   a0); else gb[2*tid]=0;
  if (a1) gb[2*tid+1] = atomicAdd(&gcur[(2*tid+1)*GCUR_STRIDE], a1); else gb[2*tid+1]=0;
  hist[2*tid]=0; hist[2*tid+1]=0;
  __syncthreads();

  // scatter into LDS stage ordered by bucket
  #pragma unroll
  for (int k=0;k<PCHUNK/256;k++){
    if (d[k]>=0){
      int b = d[k]>>BSH;
      int loc = soff[b] + atomicAdd(&hist[b],1);
      stage[loc] = (u32)s[k] | ((u32)(d[k] & ((1<<BSH)-1)) << 24);
      sbkt[loc] = (u16)b;
    }
  }
  __syncthreads();

  // coalesced flush: consecutive slots of a bucket -> consecutive global pairs
  int cnt_edges = E - base; if (cnt_edges > PCHUNK) cnt_edges = PCHUNK;
  for (int i=tid; i<cnt_edges; i+=256){
    int b = sbkt[i];
    pairs[(size_t)gb[b] + (i - soff[b])] = stage[i];
  }
}

// ---- phase 2ex: bucket-local count + scan -> row_ptr, dinv, exact scatter -
// Defensive: lcur fully initialized + scatter pos clamped to bucket window.
__global__ __launch_bounds__(256) void k_part2ex(
    const u32* __restrict__ pairs, const int* __restrict__ bbase,
    int* __restrict__ row_ptr, float* __restrict__ dinv,
    int* __restrict__ colv, int N)
{
  __shared__ int lcnt[1<<BSH];
  __shared__ int sscan[256];
  __shared__ int lcur[1<<BSH];
  int b = blockIdx.x, t = threadIdx.x;
  int n0 = b<<BSH;
  int nn = N - n0; if (nn > 256) nn = 256;
  int lo = bbase[b], hi = bbase[b+1];
  lcnt[t] = 0; lcur[t] = lo;
  __syncthreads();
  for (int i = lo + t; i < hi; i += 256)
    atomicAdd(&lcnt[pairs[i] >> 24], 1);
  __syncthreads();
  int c = lcnt[t];
  sscan[t] = c; __syncthreads();
  for (int o=1;o<256;o<<=1){ int x=(t>=o)?sscan[t-o]:0; __syncthreads(); sscan[t]+=x; __syncthreads(); }
  int pre = (t>0)?sscan[t-1]:0;
  if (t < nn){
    row_ptr[n0+t] = lo + pre;
    dinv[n0+t]    = rsqrtf((float)(c+1));   // +1 self-loop; always >0
    lcur[t]       = lo + pre;
  }
  __syncthreads();
  for (int i = lo + t; i < hi; i += 256){
    u32 p = pairs[i];
    int pos = atomicAdd(&lcur[p>>24], 1);
    if (pos >= lo && pos < hi) colv[pos] = (int)(p & 0xFFFFFFu);
  }
}

// ---- MFMA GEMM: G = dinv ⊙ (X @ W), bf16 out. 512-block grid (proven r2). -
// W comes PRE-PACKED (k_init): staging = 32 coalesced 16B loads/lane.
template <typename TIN>
__global__ __launch_bounds__(256) void k_gemm_scale(
    const TIN* __restrict__ X, const u16* __restrict__ Wp,
    const float* __restrict__ dinv, u16* __restrict__ Gout, int nrows)
{
  int lane = threadIdx.x & 63;
  int wv   = threadIdx.x >> 6;
  int n    = lane & 15, quad = lane >> 4;

  const short8* wp = reinterpret_cast<const short8*>(Wp);
  short8 bf[8][4];
  #pragma unroll
  for (int t=0;t<8;t++)
    #pragma unroll
    for (int c=0;c<4;c++)
      bf[t][c] = wp[(t*4+c)*64 + lane];

  int ntiles = (nrows+15)>>4;
  int stride = gridDim.x*4;
  for (int tile = blockIdx.x*4 + wv; tile < ntiles; tile += stride){
    int ra = tile*16 + n;                 // lane's A row (m = lane&15)
    if (ra >= nrows) ra = nrows-1;
    const TIN* xp = X + (size_t)ra*HD + quad*8;
    short8 a[4];
    #pragma unroll
    for (int c=0;c<4;c++) a[c] = load8(xp + c*32);

    f32x4 acc[8];
    #pragma unroll
    for (int t=0;t<8;t++) acc[t] = (f32x4){0.f,0.f,0.f,0.f};
    #pragma unroll
    for (int c=0;c<4;c++)
      #pragma unroll
      for (int t=0;t<8;t++)
        acc[t] = __builtin_amdgcn_mfma_f32_16x16x32_bf16(a[c], bf[t][c], acc[t], 0,0,0);

    float dv[4]; int rw[4];
    #pragma unroll
    for (int r=0;r<4;r++){
      int row = tile*16 + quad*4 + r;
      rw[r]=row; dv[r]=(row<nrows)?dinv[row]:0.f;
    }
    #pragma unroll
    for (int t=0;t<8;t++)
      #pragma unroll
      for (int r=0;r<4;r++){
        int row = rw[r];
        if (row < nrows)
          Gout[(size_t)row*HD + t*16 + n] = f2bf(dv[r]*acc[t][r]);
      }
  }
}

// ---- aggregation (r7-v3, FROZEN at service roofline) ----------------------
// h[i]=relu(dinv[i]*(g[i]+sum g[src])+b). One wave/node, u32 row loads,
// 16/8/4/scalar ladder. r8 u64-half-wave A/B: NEUTRAL -> line-service-bound
// at ~3.4 TB/s on the XCD-compulsory 220 MB. Node-range args [rn0,rn1) let
// the launch split this into quarters (diagnostic: clears top-5 for middle).
__global__ __launch_bounds__(256) void k_aggregate(
    const u16* __restrict__ g, const int* __restrict__ row_ptr,
    const int* __restrict__ colv, const float* __restrict__ dinv,
    const float* __restrict__ bias, u16* __restrict__ h, int rn0, int rn1)
{
  int node = rn0 + blockIdx.x*4 + (threadIdx.x>>6);
  if (node >= rn1) return;
  int lane = threadIdx.x & 63;
  int off = lane*2;

  u32 u = *reinterpret_cast<const u32*>(g + (size_t)node*HD + off);   // self-loop term
  float ax = blo(u), ay = bhi(u);

  int s = row_ptr[node], e = row_ptr[node+1];
  int i = s;
  for (; i+16<=e; i+=16){
    u32 v[16];
    #pragma unroll
    for (int j=0;j<16;j++)
      v[j] = *reinterpret_cast<const u32*>(g+(size_t)colv[i+j]*HD+off);
    #pragma unroll
    for (int j=0;j<16;j++){ ax += blo(v[j]); ay += bhi(v[j]); }
  }
  if (i+8<=e){
    u32 v[8];
    #pragma unroll
    for (int j=0;j<8;j++)
      v[j] = *reinterpret_cast<const u32*>(g+(size_t)colv[i+j]*HD+off);
    #pragma unroll
    for (int j=0;j<8;j++){ ax += blo(v[j]); ay += bhi(v[j]); }
    i += 8;
  }
  if (i+4<=e){
    u32 v[4];
    #pragma unroll
    for (int j=0;j<4;j++)
      v[j] = *reinterpret_cast<const u32*>(g+(size_t)colv[i+j]*HD+off);
    #pragma unroll
    for (int j=0;j<4;j++){ ax += blo(v[j]); ay += bhi(v[j]); }
    i += 4;
  }
  for (; i<e; i++){
    u32 v=*reinterpret_cast<const u32*>(g+(size_t)colv[i]*HD+off);
    ax += blo(v); ay += bhi(v);
  }

  float dv = dinv[node];
  float rx = fmaxf(fmaf(dv, ax, bias[off]),   0.f);
  float ry = fmaxf(fmaf(dv, ay, bias[off+1]), 0.f);
  *reinterpret_cast<u32*>(h + (size_t)node*HD + off) = (u32)f2bf(rx) | ((u32)f2bf(ry)<<16);
}

// ---- global_add_pool + final linear (sorted) + atomic fallback (fused) ----
__device__ __forceinline__ int lowerb(const void* a, int is32, int n, int key){
  int lo=0, hi=n;
  while (lo<hi){
    int mid=(lo+hi)>>1;
    if (idx_at(a, mid, is32) < key) lo=mid+1; else hi=mid;
  }
  return lo;
}

// Blocks [0,G): sorted path (pool + final dot); blocks [G,G+1024): atomic
// fallback (only active when batch unsorted). Exactly one side does work.
__global__ __launch_bounds__(256) void k_pool_final(
    const u16* __restrict__ h, const void* __restrict__ batch,
    const int* __restrict__ flags, const float* __restrict__ Wl,
    const float* __restrict__ bl, float* __restrict__ out,
    float* __restrict__ pooled, int n, int G)
{
  __shared__ float sd[4][128];
  __shared__ float ps[128];
  __shared__ float racc[4][64];
  int t = threadIdx.x;
  int is32 = flags[1];

  if (blockIdx.x >= G){                     // ---- atomic fallback path ----
    if (!flags[2]) return;                  // sorted path already did it
    int lane = t & 63;
    int off = lane*2;
    for (int node = (blockIdx.x-G)*4 + (t>>6); node < n; node += 1024*4){
      int g = idx_at(batch, node, is32);
      u32 v = *reinterpret_cast<const u32*>(h + (size_t)node*HD + off);
      atomicAdd(&pooled[(size_t)g*HD + off],     blo(v));
      atomicAdd(&pooled[(size_t)g*HD + off + 1], bhi(v));
    }
    return;
  }
  if (flags[2]) return;                     // unsorted -> atomic path handles it

  int gid = blockIdx.x;
  int w = t >> 6, lane = t & 63;
  int off = lane*2;
  int lo = lowerb(batch, is32, n, gid), hi = lowerb(batch, is32, n, gid+1);

  float ax = 0.f, ay = 0.f;
  int i = lo + w;                           // waves stride rows by 4
  for (; i + 12 < hi; i += 16){
    u32 v0 = *reinterpret_cast<const u32*>(h + (size_t)(i   )*HD + off);
    u32 v1 = *reinterpret_cast<const u32*>(h + (size_t)(i+ 4)*HD + off);
    u32 v2 = *reinterpret_cast<const u32*>(h + (size_t)(i+ 8)*HD + off);
    u32 v3 = *reinterpret_cast<const u32*>(h + (size_t)(i+12)*HD + off);
    ax += blo(v0)+blo(v1)+blo(v2)+blo(v3);
    ay += bhi(v0)+bhi(v1)+bhi(v2)+bhi(v3);
  }
  for (; i < hi; i += 4){
    u32 v = *reinterpret_cast<const u32*>(h + (size_t)i*HD + off);
    ax += blo(v); ay += bhi(v);
  }
  sd[w][off] = ax; sd[w][off+1] = ay;
  __syncthreads();
  if (t < 128) ps[t] = sd[0][t] + sd[1][t] + sd[2][t] + sd[3][t];
  __syncthreads();

  // out[gid] = ps @ Wl + bl : 4 k-segments of 32, 64 outputs each
  int o = t & 63, seg = t >> 6;
  float acc = 0.f;
  #pragma unroll
  for (int kk=0; kk<32; kk++){
    int k = seg*32 + kk;
    acc = fmaf(ps[k], Wl[k*OUTD + o], acc);
  }
  racc[seg][o] = acc;
  __syncthreads();
  if (t < 64)
    out[(size_t)gid*OUTD + t] = bl[t] + racc[0][t] + racc[1][t] + racc[2][t] + racc[3][t];
}

// ---- final linear, unsorted path only: out = pooled @ Wl + bl -------------
__global__ void k_final(const float* __restrict__ pooled, const float* __restrict__ Wl,
                        const float* __restrict__ bl, const int* __restrict__ flags,
                        float* __restrict__ out){
  if (!flags[2]) return;                    // sorted path wrote out already
  int gid = blockIdx.x, t = threadIdx.x;   // 64 threads
  float acc = bl[t];
  const float* p = pooled + gid*HD;
  #pragma unroll 8
  for (int k=0;k<HD;k++) acc = fmaf(p[k], Wl[k*OUTD + t], acc);
  out[gid*OUTD + t] = acc;
}

extern "C" void kernel_launch(void* const* d_in, const int* in_sizes, int n_in,
                              void* d_out, int out_size, void* d_ws, size_t ws_size,
                              hipStream_t stream)
{
  const float* x   = (const float*)d_in[0];
  const void*  ei  = d_in[1];
  const void*  bat = d_in[2];
  const float* W1  = (const float*)d_in[3];
  const float* b1  = (const float*)d_in[4];
  const float* W2  = (const float*)d_in[5];
  const float* b2  = (const float*)d_in[6];
  const float* Wl  = (const float*)d_in[7];
  const float* bl  = (const float*)d_in[8];
  float* out = (float*)d_out;

  int N = in_sizes[0] / HD;
  int E = in_sizes[1] / 2;
  int G = out_size / OUTD;
  int nbins = (N + (1<<BSH) - 1) >> BSH;   // 256 nodes per bin

  char* w = (char*)d_ws;
  size_t o = 0;
  auto alloc = [&](size_t b){ void* p = w + o; o += (b + 255) & ~(size_t)255; return p; };
  int*   row_ptr = (int*)  alloc((size_t)(N+1)*4);
  int*   colv    = (int*)  alloc((size_t)E*4);
  u32*   pairs   = (u32*)  alloc((size_t)E*4);
  int*   gcur    = (int*)  alloc((size_t)NBKT_MAX*GCUR_STRIDE*4);
  int*   bcntp   = (int*)  alloc((size_t)NBKT_MAX*GCUR_STRIDE*4);
  int*   bbase   = (int*)  alloc((size_t)(NBKT_MAX+1)*4);
  float* dinv    = (float*)alloc((size_t)N*4);
  u16*   gbuf    = (u16*)  alloc((size_t)N*HD*2);
  u16*   hbuf    = (u16*)  alloc((size_t)N*HD*2);
  float* pooled  = (float*)alloc((size_t)G*HD*4);
  u16*   wp1     = (u16*)  alloc((size_t)HD*HD*2);
  u16*   wp2     = (u16*)  alloc((size_t)HD*HD*2);
  int*   flags   = (int*)  alloc(256);
  (void)n_in;

  if (o > ws_size || nbins > NBKT_MAX){
    k_zero_out<<<(out_size+255)/256, 256, 0, stream>>>(out, out_size);
    return;
  }

  int npairs_e = 4096; if (npairs_e > E) npairs_e = E;
  int npairs_b = 4096; if (npairs_b > N/2) npairs_b = N/2;
  int npool = G*HD;
  int nbc = NBKT_MAX*GCUR_STRIDE;
  int nzb = (npool+255)/256; { int bz = (nbc+255)/256; if (bz > nzb) nzb = bz; }

  // 1: pack W1/W2 + zero flags/bcntp/pooled + dtype detection (one dispatch)
  k_init<<<3+nzb, 256, 0, stream>>>(W1, wp1, W2, wp2,
                                    (const u32*)ei, (const u32*)bat, flags, bcntp, pooled,
                                    npairs_e, npairs_b, nbc, npool);
  // 2: sortedness check + LDS-staged bucket histogram
  int NBc = (N+255)/256, NPB = (E+EPB-1)/EPB;
  k_bucket_sorted<<<NBc+NPB, 256, 0, stream>>>(bat, ei, flags, bcntp, N, E, NBc);
  // 3: 512-bucket scan -> gcur + bbase
  k_bucket_scan<<<1, 256, 0, stream>>>(bcntp, gcur, bbase, row_ptr, N, E);
  // 4: partition phase 1 (bucket-region-ordered pairs)
  int npart = (E + PCHUNK - 1) / PCHUNK;
  k_part1<<<npart, 256, 0, stream>>>(ei, flags, gcur, pairs, E);
  // 5: bucket-local count/scan -> row_ptr + dinv + exact colv scatter
  k_part2ex<<<nbins, 256, 0, stream>>>(pairs, bbase, row_ptr, dinv, colv, N);
  // 6-9: GEMM L1, aggregate L1 (x4 node-quarters), GEMM L2, aggregate L2 (x4)
  // Aggregate quarter-split is diagnostic: drops each dispatch to ~16us so
  // the top-5 profile finally shows the middle kernels (~240us unaccounted).
  int qn = (N+3)/4;
  k_gemm_scale<float><<<512, 256, 0, stream>>>(x, wp1, dinv, gbuf, N);
  for (int k=0;k<4;k++){
    int a=k*qn, b=(k+1)*qn; if (b>N) b=N;
    if (b>a) k_aggregate<<<(b-a+3)/4, 256, 0, stream>>>(gbuf, row_ptr, colv, dinv, b1, hbuf, a, b);
  }
  k_gemm_scale<u16><<<512, 256, 0, stream>>>(hbuf, wp2, dinv, gbuf, N);
  for (int k=0;k<4;k++){
    int a=k*qn, b=(k+1)*qn; if (b>N) b=N;
    if (b>a) k_aggregate<<<(b-a+3)/4, 256, 0, stream>>>(gbuf, row_ptr, colv, dinv, b2, hbuf, a, b);
  }
  // 10-11: pool+final fused (sorted + atomic fallback in one dispatch)
  k_pool_final<<<G+1024, 256, 0, stream>>>(hbuf, bat, flags, Wl, bl, out, pooled, N, G);
  k_final     <<<G, OUTD, 0, stream>>>(pooled, Wl, bl, flags, out);
}

// Round 10
// 364.340 us; speedup vs baseline: 1.0809x; 1.0809x over previous
//
#include <hip/hip_runtime.h>
#include <hip/hip_bf16.h>

typedef unsigned short u16;
typedef unsigned int   u32;
typedef unsigned long long u64;
typedef long long      i64;
typedef __attribute__((ext_vector_type(8))) short short8;  // 8 bf16 raw
typedef __attribute__((ext_vector_type(4))) float f32x4;

#define HD 128   // hidden / input feature dim
#define OUTD 64  // final output dim
#define BSH 8            // bucket shift: 256 nodes per bucket (power of 2, <=8 for u32 pack!)
#define NBKT_MAX 512     // max buckets (N <= 128K; also keeps src in 24 bits)
#define PCHUNK 2048      // edges per block in partition phase 1
#define EPB 4096         // edges per block in bucket histogram
#define GCUR_STRIDE 16   // ints; 64 B padding to avoid atomic line contention

__device__ __forceinline__ float bf2f(u16 u){ union{u32 i; float f;} x; x.i=((u32)u)<<16; return x.f; }
__device__ __forceinline__ u16 f2bf(float f){ __hip_bfloat16 h=__float2bfloat16(f); return *reinterpret_cast<u16*>(&h); }
__device__ __forceinline__ float blo(u32 v){ union{u32 i; float f;} x; x.i=v<<16; return x.f; }
__device__ __forceinline__ float bhi(u32 v){ union{u32 i; float f;} x; x.i=v&0xffff0000u; return x.f; }

__device__ __forceinline__ short8 load8(const float* p){
  f32x4 lo = *reinterpret_cast<const f32x4*>(p);
  f32x4 hi = *reinterpret_cast<const f32x4*>(p + 4);
  short8 r;
  #pragma unroll
  for (int j=0;j<4;j++){ r[j]=(short)f2bf(lo[j]); r[4+j]=(short)f2bf(hi[j]); }
  return r;
}
__device__ __forceinline__ short8 load8(const u16* p){
  return *reinterpret_cast<const short8*>(p);
}

// index fetch that handles int32-vs-int64 delivery (flag: 1 = int32, 0 = int64)
__device__ __forceinline__ int idx_at(const void* p, int i, int is32){
  return is32 ? ((const int*)p)[i] : (int)((const i64*)p)[i];
}

// ---- zero-fill output (ws-too-small fallback signal) ----------------------
__global__ void k_zero_out(float* __restrict__ out, int n){
  int i = blockIdx.x*256 + threadIdx.x;
  if (i < n) out[i] = 0.f;
}

// ---- init (fused): blocks 0-1 pack W1/W2 -> bf16 fragment-major; block 2 =
// zero+detect dtype flags; blocks >=3 zero bcntp/pooled. -------------------
// flags[0]=edge int32?, flags[1]=batch int32?, flags[2]=batch unsorted?
__global__ __launch_bounds__(256) void k_init(
    const float* __restrict__ W1, u16* __restrict__ Wp1,
    const float* __restrict__ W2, u16* __restrict__ Wp2,
    const u32* __restrict__ ei, const u32* __restrict__ bw,
    int* __restrict__ flags, int* __restrict__ bcntp, float* __restrict__ pooled,
    int npairs_e, int npairs_b, int nbc, int npool)
{
  int t = threadIdx.x;
  if (blockIdx.x < 2){
    const float* W  = blockIdx.x ? W2 : W1;
    u16*         Wp = blockIdx.x ? Wp2 : Wp1;
    for (int u = t; u < 2048; u += 256){
      int lane = u & 63, tc = u >> 6;
      int tt = tc >> 2, c = tc & 3;
      int n = lane & 15, quad = lane >> 4;
      #pragma unroll
      for (int j=0;j<8;j++)
        Wp[(size_t)u*8 + j] = f2bf(W[(c*32 + quad*8 + j)*HD + tt*16 + n]);
    }
  } else if (blockIdx.x == 2){
    if (t < 16) flags[t] = 0;
    __syncthreads();
    for (int i=t; i<npairs_e; i+=256) if (ei[2*i+1] != 0) atomicOr(&flags[0], 1);
    for (int i=t; i<npairs_b; i+=256) if (bw[2*i+1] != 0) atomicOr(&flags[1], 1);
  } else {
    int i = (blockIdx.x-3)*256 + t;
    if (i < nbc)   bcntp[i] = 0;
    if (i < npool) pooled[i] = 0.f;
  }
}

// ---- bucket histogram + sortedness check ----------------------------------
// LDS 512-bin histogram/block, then 2 padded-line global atomics per thread.
// Per-NODE degrees are derived later, bucket-locally, in k_part2ex.
__global__ __launch_bounds__(256) void k_bucket_sorted(
    const void* __restrict__ batch, const void* __restrict__ ei,
    int* __restrict__ flags, int* __restrict__ bcntp, int n, int E, int NBc)
{
  __shared__ int hist[NBKT_MAX];
  int tid = threadIdx.x;
  if (blockIdx.x < NBc){
    int i = blockIdx.x*256 + tid;
    if (i < n-1){
      int is32 = flags[1];
      if (idx_at(batch, i, is32) > idx_at(batch, i+1, is32)) atomicOr(&flags[2], 1);
    }
    return;
  }
  hist[tid]=0; hist[tid+256]=0;
  __syncthreads();
  int base = (blockIdx.x - NBc)*EPB;
  int is32 = flags[0];
  #pragma unroll
  for (int k=0;k<EPB/256;k++){
    int e = base + k*256 + tid;
    if (e < E){
      int d = idx_at(ei, E + e, is32);   // dst = row 1
      atomicAdd(&hist[d>>BSH], 1);
    }
  }
  __syncthreads();
  int a0=hist[2*tid], a1=hist[2*tid+1];
  if (a0) atomicAdd(&bcntp[(2*tid)*GCUR_STRIDE],   a0);
  if (a1) atomicAdd(&bcntp[(2*tid+1)*GCUR_STRIDE], a1);
}

// ---- 512-bucket exclusive scan -> bucket bases (gcur for part1, bbase) ----
__global__ __launch_bounds__(256) void k_bucket_scan(
    const int* __restrict__ bcntp, int* __restrict__ gcur, int* __restrict__ bbase,
    int* __restrict__ row_ptr, int N, int E)
{
  __shared__ int scant[256];
  int t = threadIdx.x;
  int a0 = bcntp[(2*t)*GCUR_STRIDE], a1 = bcntp[(2*t+1)*GCUR_STRIDE];
  scant[t] = a0 + a1; __syncthreads();
  for (int o=1;o<256;o<<=1){ int x=(t>=o)?scant[t-o]:0; __syncthreads(); scant[t]+=x; __syncthreads(); }
  int pre = (t>0)?scant[t-1]:0;
  gcur[(2*t)*GCUR_STRIDE]   = pre;      bbase[2*t]   = pre;
  gcur[(2*t+1)*GCUR_STRIDE] = pre + a0; bbase[2*t+1] = pre + a0;
  if (t == 255){ bbase[512] = pre + a0 + a1; row_ptr[N] = E; }
}

// ---- phase 1: LDS-staged partition of edges into dst-buckets --------------
// STANDALONE kernel (low VGPR): r3's fat-fuse with the GEMM forced 144 VGPRs
// on these blocks and cut occupancy 8->3 blocks/CU (91 us, all pipes idle).
// pairs entry: src in bits [0,24), dst_local (d & 255) in bits [24,32).
__global__ __launch_bounds__(256) void k_part1(
    const void* __restrict__ ei, const int* __restrict__ flags,
    int* __restrict__ gcur, u32* __restrict__ pairs, int E)
{
  __shared__ int hist[NBKT_MAX];
  __shared__ int soff[NBKT_MAX];
  __shared__ int gb[NBKT_MAX];
  __shared__ int scant[256];
  __shared__ u32 stage[PCHUNK];
  __shared__ u16 sbkt[PCHUNK];

  int tid = threadIdx.x;
  hist[tid]=0; hist[tid+256]=0;
  __syncthreads();

  int base = blockIdx.x*PCHUNK;
  int is32 = flags[0];
  int d[PCHUNK/256], s[PCHUNK/256];
  #pragma unroll
  for (int k=0;k<PCHUNK/256;k++){
    int e = base + k*256 + tid;
    if (e < E){
      d[k]=idx_at(ei,E+e,is32); s[k]=idx_at(ei,e,is32);
      atomicAdd(&hist[d[k]>>BSH],1);
    } else d[k]=-1;
  }
  __syncthreads();

  // scan 512 buckets with 256 threads (2 each)
  int a0=hist[2*tid], a1=hist[2*tid+1];
  scant[tid]=a0+a1; __syncthreads();
  for (int o=1;o<256;o<<=1){ int x2=(tid>=o)?scant[tid-o]:0; __syncthreads(); scant[tid]+=x2; __syncthreads(); }
  int pre = (tid>0)?scant[tid-1]:0;
  soff[2*tid]=pre; soff[2*tid+1]=pre+a0;
  if (a0) gb[2*tid]   = atomicAdd(&gcur[(2*tid)*GCUR_STRIDE],   a0); else gb[2*tid]=0;
  if (a1) gb[2*tid+1] = atomicAdd(&gcur[(2*tid+1)*GCUR_STRIDE], a1); else gb[2*tid+1]=0;
  hist[2*tid]=0; hist[2*tid+1]=0;
  __syncthreads();

  // scatter into LDS stage ordered by bucket
  #pragma unroll
  for (int k=0;k<PCHUNK/256;k++){
    if (d[k]>=0){
      int b = d[k]>>BSH;
      int loc = soff[b] + atomicAdd(&hist[b],1);
      stage[loc] = (u32)s[k] | ((u32)(d[k] & ((1<<BSH)-1)) << 24);
      sbkt[loc] = (u16)b;
    }
  }
  __syncthreads();

  // coalesced flush: consecutive slots of a bucket -> consecutive global pairs
  int cnt_edges = E - base; if (cnt_edges > PCHUNK) cnt_edges = PCHUNK;
  for (int i=tid; i<cnt_edges; i+=256){
    int b = sbkt[i];
    pairs[(size_t)gb[b] + (i - soff[b])] = stage[i];
  }
}

// ---- phase 2ex: bucket-local count + scan -> row_ptr, dinv, exact scatter -
// Defensive: lcur fully initialized + scatter pos clamped to bucket window.
__global__ __launch_bounds__(256) void k_part2ex(
    const u32* __restrict__ pairs, const int* __restrict__ bbase,
    int* __restrict__ row_ptr, float* __restrict__ dinv,
    int* __restrict__ colv, int N)
{
  __shared__ int lcnt[1<<BSH];
  __shared__ int sscan[256];
  __shared__ int lcur[1<<BSH];
  int b = blockIdx.x, t = threadIdx.x;
  int n0 = b<<BSH;
  int nn = N - n0; if (nn > 256) nn = 256;
  int lo = bbase[b], hi = bbase[b+1];
  lcnt[t] = 0; lcur[t] = lo;
  __syncthreads();
  for (int i = lo + t; i < hi; i += 256)
    atomicAdd(&lcnt[pairs[i] >> 24], 1);
  __syncthreads();
  int c = lcnt[t];
  sscan[t] = c; __syncthreads();
  for (int o=1;o<256;o<<=1){ int x=(t>=o)?sscan[t-o]:0; __syncthreads(); sscan[t]+=x; __syncthreads(); }
  int pre = (t>0)?sscan[t-1]:0;
  if (t < nn){
    row_ptr[n0+t] = lo + pre;
    dinv[n0+t]    = rsqrtf((float)(c+1));   // +1 self-loop; always >0
    lcur[t]       = lo + pre;
  }
  __syncthreads();
  for (int i = lo + t; i < hi; i += 256){
    u32 p = pairs[i];
    int pos = atomicAdd(&lcur[p>>24], 1);
    if (pos >= lo && pos < hi) colv[pos] = (int)(p & 0xFFFFFFu);
  }
}

// ---- MFMA GEMM: G = dinv ⊙ (X @ W), bf16 out. ------------------------------
// W PRE-PACKED (k_init): staging = 32 coalesced 16B loads/lane (L2-hot).
// Grid 1024 (r9 profile: grid 512 = 2 blocks/CU = 15% occupancy, 41.6us
// latency-bound at 3.4x memory floor; 104 VGPR allows 4 blocks/CU -> 1024).
template <typename TIN>
__global__ __launch_bounds__(256) void k_gemm_scale(
    const TIN* __restrict__ X, const u16* __restrict__ Wp,
    const float* __restrict__ dinv, u16* __restrict__ Gout, int nrows)
{
  int lane = threadIdx.x & 63;
  int wv   = threadIdx.x >> 6;
  int n    = lane & 15, quad = lane >> 4;

  const short8* wp = reinterpret_cast<const short8*>(Wp);
  short8 bf[8][4];
  #pragma unroll
  for (int t=0;t<8;t++)
    #pragma unroll
    for (int c=0;c<4;c++)
      bf[t][c] = wp[(t*4+c)*64 + lane];

  int ntiles = (nrows+15)>>4;
  int stride = gridDim.x*4;
  for (int tile = blockIdx.x*4 + wv; tile < ntiles; tile += stride){
    int ra = tile*16 + n;                 // lane's A row (m = lane&15)
    if (ra >= nrows) ra = nrows-1;
    const TIN* xp = X + (size_t)ra*HD + quad*8;
    short8 a[4];
    #pragma unroll
    for (int c=0;c<4;c++) a[c] = load8(xp + c*32);

    f32x4 acc[8];
    #pragma unroll
    for (int t=0;t<8;t++) acc[t] = (f32x4){0.f,0.f,0.f,0.f};
    #pragma unroll
    for (int c=0;c<4;c++)
      #pragma unroll
      for (int t=0;t<8;t++)
        acc[t] = __builtin_amdgcn_mfma_f32_16x16x32_bf16(a[c], bf[t][c], acc[t], 0,0,0);

    float dv[4]; int rw[4];
    #pragma unroll
    for (int r=0;r<4;r++){
      int row = tile*16 + quad*4 + r;
      rw[r]=row; dv[r]=(row<nrows)?dinv[row]:0.f;
    }
    #pragma unroll
    for (int t=0;t<8;t++)
      #pragma unroll
      for (int r=0;r<4;r++){
        int row = rw[r];
        if (row < nrows)
          Gout[(size_t)row*HD + t*16 + n] = f2bf(dv[r]*acc[t][r]);
      }
  }
}

// ---- aggregation (r7-v3, FROZEN at service roofline) ----------------------
// h[i]=relu(dinv[i]*(g[i]+sum g[src])+b). One wave/node, u32 row loads,
// 16/8/4/scalar ladder. r8 u64-half-wave A/B: NEUTRAL -> line-service-bound
// at ~3.4 TB/s on the XCD-compulsory 220 MB. Do NOT touch.
__global__ __launch_bounds__(256) void k_aggregate(
    const u16* __restrict__ g, const int* __restrict__ row_ptr,
    const int* __restrict__ colv, const float* __restrict__ dinv,
    const float* __restrict__ bias, u16* __restrict__ h, int n)
{
  int node = blockIdx.x*4 + (threadIdx.x>>6);
  if (node >= n) return;
  int lane = threadIdx.x & 63;
  int off = lane*2;

  u32 u = *reinterpret_cast<const u32*>(g + (size_t)node*HD + off);   // self-loop term
  float ax = blo(u), ay = bhi(u);

  int s = row_ptr[node], e = row_ptr[node+1];
  int i = s;
  for (; i+16<=e; i+=16){
    u32 v[16];
    #pragma unroll
    for (int j=0;j<16;j++)
      v[j] = *reinterpret_cast<const u32*>(g+(size_t)colv[i+j]*HD+off);
    #pragma unroll
    for (int j=0;j<16;j++){ ax += blo(v[j]); ay += bhi(v[j]); }
  }
  if (i+8<=e){
    u32 v[8];
    #pragma unroll
    for (int j=0;j<8;j++)
      v[j] = *reinterpret_cast<const u32*>(g+(size_t)colv[i+j]*HD+off);
    #pragma unroll
    for (int j=0;j<8;j++){ ax += blo(v[j]); ay += bhi(v[j]); }
    i += 8;
  }
  if (i+4<=e){
    u32 v[4];
    #pragma unroll
    for (int j=0;j<4;j++)
      v[j] = *reinterpret_cast<const u32*>(g+(size_t)colv[i+j]*HD+off);
    #pragma unroll
    for (int j=0;j<4;j++){ ax += blo(v[j]); ay += bhi(v[j]); }
    i += 4;
  }
  for (; i<e; i++){
    u32 v=*reinterpret_cast<const u32*>(g+(size_t)colv[i]*HD+off);
    ax += blo(v); ay += bhi(v);
  }

  float dv = dinv[node];
  float rx = fmaxf(fmaf(dv, ax, bias[off]),   0.f);
  float ry = fmaxf(fmaf(dv, ay, bias[off+1]), 0.f);
  *reinterpret_cast<u32*>(h + (size_t)node*HD + off) = (u32)f2bf(rx) | ((u32)f2bf(ry)<<16);
}

// ---- global_add_pool + final linear (sorted) + atomic fallback (fused) ----
__device__ __forceinline__ int lowerb(const void* a, int is32, int n, int key){
  int lo=0, hi=n;
  while (lo<hi){
    int mid=(lo+hi)>>1;
    if (idx_at(a, mid, is32) < key) lo=mid+1; else hi=mid;
  }
  return lo;
}

// Blocks [0,G): sorted path (pool + final dot); blocks [G,G+1024): atomic
// fallback (only active when batch unsorted). Exactly one side does work.
__global__ __launch_bounds__(256) void k_pool_final(
    const u16* __restrict__ h, const void* __restrict__ batch,
    const int* __restrict__ flags, const float* __restrict__ Wl,
    const float* __restrict__ bl, float* __restrict__ out,
    float* __restrict__ pooled, int n, int G)
{
  __shared__ float sd[4][128];
  __shared__ float ps[128];
  __shared__ float racc[4][64];
  int t = threadIdx.x;
  int is32 = flags[1];

  if (blockIdx.x >= G){                     // ---- atomic fallback path ----
    if (!flags[2]) return;                  // sorted path already did it
    int lane = t & 63;
    int off = lane*2;
    for (int node = (blockIdx.x-G)*4 + (t>>6); node < n; node += 1024*4){
      int g = idx_at(batch, node, is32);
      u32 v = *reinterpret_cast<const u32*>(h + (size_t)node*HD + off);
      atomicAdd(&pooled[(size_t)g*HD + off],     blo(v));
      atomicAdd(&pooled[(size_t)g*HD + off + 1], bhi(v));
    }
    return;
  }
  if (flags[2]) return;                     // unsorted -> atomic path handles it

  int gid = blockIdx.x;
  int w = t >> 6, lane = t & 63;
  int off = lane*2;
  int lo = lowerb(batch, is32, n, gid), hi = lowerb(batch, is32, n, gid+1);

  float ax = 0.f, ay = 0.f;
  int i = lo + w;                           // waves stride rows by 4
  for (; i + 12 < hi; i += 16){
    u32 v0 = *reinterpret_cast<const u32*>(h + (size_t)(i   )*HD + off);
    u32 v1 = *reinterpret_cast<const u32*>(h + (size_t)(i+ 4)*HD + off);
    u32 v2 = *reinterpret_cast<const u32*>(h + (size_t)(i+ 8)*HD + off);
    u32 v3 = *reinterpret_cast<const u32*>(h + (size_t)(i+12)*HD + off);
    ax += blo(v0)+blo(v1)+blo(v2)+blo(v3);
    ay += bhi(v0)+bhi(v1)+bhi(v2)+bhi(v3);
  }
  for (; i < hi; i += 4){
    u32 v = *reinterpret_cast<const u32*>(h + (size_t)i*HD + off);
    ax += blo(v); ay += bhi(v);
  }
  sd[w][off] = ax; sd[w][off+1] = ay;
  __syncthreads();
  if (t < 128) ps[t] = sd[0][t] + sd[1][t] + sd[2][t] + sd[3][t];
  __syncthreads();

  // out[gid] = ps @ Wl + bl : 4 k-segments of 32, 64 outputs each
  int o = t & 63, seg = t >> 6;
  float acc = 0.f;
  #pragma unroll
  for (int kk=0; kk<32; kk++){
    int k = seg*32 + kk;
    acc = fmaf(ps[k], Wl[k*OUTD + o], acc);
  }
  racc[seg][o] = acc;
  __syncthreads();
  if (t < 64)
    out[(size_t)gid*OUTD + t] = bl[t] + racc[0][t] + racc[1][t] + racc[2][t] + racc[3][t];
}

// ---- final linear, unsorted path only: out = pooled @ Wl + bl -------------
__global__ void k_final(const float* __restrict__ pooled, const float* __restrict__ Wl,
                        const float* __restrict__ bl, const int* __restrict__ flags,
                        float* __restrict__ out){
  if (!flags[2]) return;                    // sorted path wrote out already
  int gid = blockIdx.x, t = threadIdx.x;   // 64 threads
  float acc = bl[t];
  const float* p = pooled + gid*HD;
  #pragma unroll 8
  for (int k=0;k<HD;k++) acc = fmaf(p[k], Wl[k*OUTD + t], acc);
  out[gid*OUTD + t] = acc;
}

extern "C" void kernel_launch(void* const* d_in, const int* in_sizes, int n_in,
                              void* d_out, int out_size, void* d_ws, size_t ws_size,
                              hipStream_t stream)
{
  const float* x   = (const float*)d_in[0];
  const void*  ei  = d_in[1];
  const void*  bat = d_in[2];
  const float* W1  = (const float*)d_in[3];
  const float* b1  = (const float*)d_in[4];
  const float* W2  = (const float*)d_in[5];
  const float* b2  = (const float*)d_in[6];
  const float* Wl  = (const float*)d_in[7];
  const float* bl  = (const float*)d_in[8];
  float* out = (float*)d_out;

  int N = in_sizes[0] / HD;
  int E = in_sizes[1] / 2;
  int G = out_size / OUTD;
  int nbins = (N + (1<<BSH) - 1) >> BSH;   // 256 nodes per bin

  char* w = (char*)d_ws;
  size_t o = 0;
  auto alloc = [&](size_t b){ void* p = w + o; o += (b + 255) & ~(size_t)255; return p; };
  int*   row_ptr = (int*)  alloc((size_t)(N+1)*4);
  int*   colv    = (int*)  alloc((size_t)E*4);
  u32*   pairs   = (u32*)  alloc((size_t)E*4);
  int*   gcur    = (int*)  alloc((size_t)NBKT_MAX*GCUR_STRIDE*4);
  int*   bcntp   = (int*)  alloc((size_t)NBKT_MAX*GCUR_STRIDE*4);
  int*   bbase   = (int*)  alloc((size_t)(NBKT_MAX+1)*4);
  float* dinv    = (float*)alloc((size_t)N*4);
  u16*   gbuf    = (u16*)  alloc((size_t)N*HD*2);
  u16*   hbuf    = (u16*)  alloc((size_t)N*HD*2);
  float* pooled  = (float*)alloc((size_t)G*HD*4);
  u16*   wp1     = (u16*)  alloc((size_t)HD*HD*2);
  u16*   wp2     = (u16*)  alloc((size_t)HD*HD*2);
  int*   flags   = (int*)  alloc(256);
  (void)n_in;

  if (o > ws_size || nbins > NBKT_MAX){
    k_zero_out<<<(out_size+255)/256, 256, 0, stream>>>(out, out_size);
    return;
  }

  int npairs_e = 4096; if (npairs_e > E) npairs_e = E;
  int npairs_b = 4096; if (npairs_b > N/2) npairs_b = N/2;
  int npool = G*HD;
  int nbc = NBKT_MAX*GCUR_STRIDE;
  int nzb = (npool+255)/256; { int bz = (nbc+255)/256; if (bz > nzb) nzb = bz; }

  // 1: pack W1/W2 + zero flags/bcntp/pooled + dtype detection (one dispatch)
  k_init<<<3+nzb, 256, 0, stream>>>(W1, wp1, W2, wp2,
                                    (const u32*)ei, (const u32*)bat, flags, bcntp, pooled,
                                    npairs_e, npairs_b, nbc, npool);
  // 2: sortedness check + LDS-staged bucket histogram
  int NBc = (N+255)/256, NPB = (E+EPB-1)/EPB;
  k_bucket_sorted<<<NBc+NPB, 256, 0, stream>>>(bat, ei, flags, bcntp, N, E, NBc);
  // 3: 512-bucket scan -> gcur + bbase
  k_bucket_scan<<<1, 256, 0, stream>>>(bcntp, gcur, bbase, row_ptr, N, E);
  // 4: partition phase 1 (bucket-region-ordered pairs)
  int npart = (E + PCHUNK - 1) / PCHUNK;
  k_part1<<<npart, 256, 0, stream>>>(ei, flags, gcur, pairs, E);
  // 5: bucket-local count/scan -> row_ptr + dinv + exact colv scatter
  k_part2ex<<<nbins, 256, 0, stream>>>(pairs, bbase, row_ptr, dinv, colv, N);
  // 6-9: GEMM L1, aggregate L1, GEMM L2, aggregate L2 (GEMM grid 1024: r9
  // showed 512 = 15% occupancy latency-bound; 1024 = VGPR-allowed 4 blk/CU)
  k_gemm_scale<float><<<1024, 256, 0, stream>>>(x, wp1, dinv, gbuf, N);
  k_aggregate <<<(N+3)/4, 256, 0, stream>>>(gbuf, row_ptr, colv, dinv, b1, hbuf, N);
  k_gemm_scale<u16><<<1024, 256, 0, stream>>>(hbuf, wp2, dinv, gbuf, N);
  k_aggregate <<<(N+3)/4, 256, 0, stream>>>(gbuf, row_ptr, colv, dinv, b2, hbuf, N);
  // 10-11: pool+final fused (sorted + atomic fallback in one dispatch)
  k_pool_final<<<G+1024, 256, 0, stream>>>(hbuf, bat, flags, Wl, bl, out, pooled, N, G);
  k_final     <<<G, OUTD, 0, stream>>>(pooled, Wl, bl, flags, out);
}